// Round 10
// baseline (307.468 us; speedup 1.0000x reference)
//
#include <hip/hip_runtime.h>

typedef unsigned short u16;
typedef unsigned int u32;
typedef short s16x8 __attribute__((ext_vector_type(8)));
typedef u16 u16x8 __attribute__((ext_vector_type(8)));
typedef float f32x4 __attribute__((ext_vector_type(4)));

#define TOK 8192
#define DM 1024
#define DI 2048
#define DS 16
#define DR 64
#define NCHUNK 64
#define CH 32
#define XPN 96
#define XP_SPLIT 4
#define CONV_T 16

#define SBAR() do { asm volatile("" ::: "memory"); __builtin_amdgcn_s_barrier(); asm volatile("" ::: "memory"); } while (0)
#define WAITVM(N) do { asm volatile("s_waitcnt vmcnt(" #N ")" ::: "memory"); __builtin_amdgcn_sched_barrier(0); } while (0)
#define WAITLGKM0() do { asm volatile("s_waitcnt lgkmcnt(0)" ::: "memory"); __builtin_amdgcn_sched_barrier(0); } while (0)

__device__ __forceinline__ u16 f2bf(float f) {
    u32 u = __float_as_uint(f);
    u32 r = (u + 0x7fffu + ((u >> 16) & 1u)) >> 16;
    return (u16)r;
}
__device__ __forceinline__ float bf2f(u16 h) {
    return __uint_as_float(((u32)h) << 16);
}
// fast softplus: v_exp_f32 + v_log_f32 (~4 VALU) instead of OCML log1pf (r5: 80us VALU-bound epilogue)
__device__ __forceinline__ float softplus_f(float x) {
    return (x > 15.f) ? x : __logf(1.f + __expf(x));
}
__device__ __forceinline__ void unpack8(const uint4 v, float* o) {
    o[0] = __uint_as_float(v.x << 16); o[1] = __uint_as_float(v.x & 0xffff0000u);
    o[2] = __uint_as_float(v.y << 16); o[3] = __uint_as_float(v.y & 0xffff0000u);
    o[4] = __uint_as_float(v.z << 16); o[5] = __uint_as_float(v.z & 0xffff0000u);
    o[6] = __uint_as_float(v.w << 16); o[7] = __uint_as_float(v.w & 0xffff0000u);
}
__device__ __forceinline__ void async16(u16* lds, const u16* g) {
    __builtin_amdgcn_global_load_lds(
        (const __attribute__((address_space(1))) void*)g,
        (__attribute__((address_space(3))) void*)lds, 16, 0, 0);
}

// ---------------- fused weight cvt (f32->bf16) + th/sd prep ----------------
__global__ __launch_bounds__(256) void cvt_all(
    const float* __restrict__ in_w, const float* __restrict__ xp_w,
    const float* __restrict__ dt_w, const float* __restrict__ out_w,
    const float* __restrict__ tau, const float* __restrict__ log_decay,
    u16* __restrict__ wi, u16* __restrict__ wxp, u16* __restrict__ wdt,
    u16* __restrict__ wout, float* __restrict__ th, float* __restrict__ sd) {
    const int b = blockIdx.x;
    const float* src; u16* dst; int i;
    if (b < 4096)      { src = in_w;  dst = wi;   i = b * 256 + threadIdx.x; }
    else if (b < 4288) { src = xp_w;  dst = wxp;  i = (b - 4096) * 256 + threadIdx.x; }
    else if (b < 4416) { src = dt_w;  dst = wdt;  i = (b - 4288) * 256 + threadIdx.x; }
    else if (b < 6464) { src = out_w; dst = wout; i = (b - 4416) * 256 + threadIdx.x; }
    else {
        int j = (b - 6464) * 256 + threadIdx.x;
        if (j < TOK) th[j] = fmaxf(tau[j] * (1.f / 3600.f), 1e-4f);
        if (j < DM)  sd[j] = softplus_f(log_decay[j]);
        return;
    }
    float4 v = ((const float4*)src)[i];
    ushort4 o;
    o.x = f2bf(v.x); o.y = f2bf(v.y); o.z = f2bf(v.z); o.w = f2bf(v.w);
    ((ushort4*)dst)[i] = o;
}

// ---------------- LayerNorm -> bf16 ----------------
__global__ __launch_bounds__(256) void ln_kernel(const float* __restrict__ x,
                                                 const float* __restrict__ g,
                                                 const float* __restrict__ bb,
                                                 u16* __restrict__ xn) {
    const int tok = blockIdx.x;
    const float4 v = ((const float4*)(x + (size_t)tok * DM))[threadIdx.x];
    float s = v.x + v.y + v.z + v.w;
    float sq = v.x * v.x + v.y * v.y + v.z * v.z + v.w * v.w;
#pragma unroll
    for (int off = 32; off; off >>= 1) {
        s += __shfl_xor(s, off);
        sq += __shfl_xor(sq, off);
    }
    __shared__ float red[8];
    const int wv = threadIdx.x >> 6;
    if ((threadIdx.x & 63) == 0) { red[wv] = s; red[4 + wv] = sq; }
    __syncthreads();
    s = red[0] + red[1] + red[2] + red[3];
    sq = red[4] + red[5] + red[6] + red[7];
    const float mean = s * (1.f / DM);
    const float var = sq * (1.f / DM) - mean * mean;
    const float rstd = rsqrtf(var + 1e-5f);
    const float4 gv = ((const float4*)g)[threadIdx.x];
    const float4 bv = ((const float4*)bb)[threadIdx.x];
    ushort4 o;
    o.x = f2bf((v.x - mean) * rstd * gv.x + bv.x);
    o.y = f2bf((v.y - mean) * rstd * gv.y + bv.y);
    o.z = f2bf((v.z - mean) * rstd * gv.z + bv.z);
    o.w = f2bf((v.w - mean) * rstd * gv.w + bv.w);
    ((ushort4*)(xn + (size_t)tok * DM))[threadIdx.x] = o;
}

// ============ 128x128 GEMM, BK=64, 4 waves (2m x 2n), dbuf=2, 2 blocks/CU ============
// r8/r9 lesson: with ONE block/CU all waves are barrier-lockstep, so per-tile LDS reads
// (~2300cyc/CU) serialize with MFMA (~2350cyc/CU) -> MfmaUtil stuck ~36%. Two INDEPENDENT
// blocks per CU (64KB LDS each, launch_bounds(256,2)) let block A's MFMA cluster overlap
// block B's ds_read/stage section. Per tile: 16 ds_reads -> lgkm0 -> bar -> stage t+2 ->
// 32 MFMA (setprio) -> vmcnt(8) -> bar.
// EPI 0 (in_proj): C -> xi (cols<2048) / z (cols>=2048), bf16.
// EPI 2 (out_proj): Cf = xres + C * exp(-sd[col]*th[row]), f32.
template <int EPI>
__global__ __launch_bounds__(256, 2) void gemm128(
    const u16* __restrict__ A, int lda,
    const u16* __restrict__ W, int ldw, int K,
    u16* __restrict__ Cxi, u16* __restrict__ Cz,
    float* __restrict__ Cf,
    const float* __restrict__ xres, const float* __restrict__ th,
    const float* __restrict__ sd) {
    __shared__ __align__(16) u16 lds[2 * 16384];  // 64 KB: per buf A 16KB + B 16KB
    const int tid = threadIdx.x;
    const int wave = tid >> 6, lane = tid & 63;
    const int wm = wave >> 1, wn = wave & 1;
    const int fl = lane & 15, fh = lane >> 4;
    // XCD swizzle + 2-D L2 region blocking
    int bm, bn;
    if (EPI == 0) {
        // in_proj: 2048 blocks, 256/XCD; region 4bm x 8bn (A 1MB + W 2MB = 3MB <= L2)
        const int swz = ((int)blockIdx.x & 7) * 256 + ((int)blockIdx.x >> 3);
        const int rg = swz >> 5, wi_ = swz & 31;
        bm = (rg >> 2) * 4 + (wi_ >> 3);   // 0..63
        bn = (rg & 3) * 8 + (wi_ & 7);     // 0..31
    } else {
        // out_proj: 512 blocks, 64/XCD; region 4bm x 4bn (A 2MB + W 2MB = 4MB = L2)
        const int swz = ((int)blockIdx.x & 7) * 64 + ((int)blockIdx.x >> 3);
        const int rg = swz >> 4, wi_ = swz & 15;
        bm = (rg >> 1) * 4 + (wi_ >> 2);   // 0..63
        bn = (rg & 1) * 4 + (wi_ & 3);     // 0..7
    }
    const int NT = K >> 6;

    const int r0 = tid >> 3;                         // 0..31
    const int cb = ((tid & 7) ^ (r0 & 7)) << 3;      // pre-swizzled col (elems)
    const int rA = bm * 128 + r0;
    const int rB = bn * 128 + r0;

    f32x4 acc[4][4];
#pragma unroll
    for (int m = 0; m < 4; m++)
#pragma unroll
        for (int n = 0; n < 4; n++) acc[m][n] = f32x4{0.f, 0.f, 0.f, 0.f};

    auto stage = [&](int buf, int k0) {
#pragma unroll
        for (int j = 0; j < 4; j++)
            async16(lds + buf * 16384 + j * 2048 + tid * 8,
                    A + (size_t)(rA + j * 32) * lda + k0 + cb);
#pragma unroll
        for (int j = 0; j < 4; j++)
            async16(lds + buf * 16384 + 8192 + j * 2048 + tid * 8,
                    W + (size_t)(rB + j * 32) * ldw + k0 + cb);
    };
    auto rdA = [&](int buf, int mf, int kk) -> s16x8 {
        int r = wm * 64 + mf * 16 + fl;
        int slot = ((kk << 2) | fh) ^ (fl & 7);
        return *(const s16x8*)(lds + buf * 16384 + r * 64 + slot * 8);
    };
    auto rdB = [&](int buf, int nf, int kk) -> s16x8 {
        int r = wn * 64 + nf * 16 + fl;
        int slot = ((kk << 2) | fh) ^ (fl & 7);
        return *(const s16x8*)(lds + buf * 16384 + 8192 + r * 64 + slot * 8);
    };

    // prologue: stage tile0 -> buf0, tile1 -> buf1; certify tile0 for all waves
    stage(0, 0);
    stage(1, 64);
    WAITVM(8);
    SBAR();

    for (int t = 0; t < NT; ++t) {
        const int cur = t & 1;
        s16x8 ah[4][2], bh[4][2];
#pragma unroll
        for (int mf = 0; mf < 4; mf++) { ah[mf][0] = rdA(cur, mf, 0); ah[mf][1] = rdA(cur, mf, 1); }
#pragma unroll
        for (int nf = 0; nf < 4; nf++) { bh[nf][0] = rdB(cur, nf, 0); bh[nf][1] = rdB(cur, nf, 1); }
        WAITLGKM0();
        SBAR();                                      // all waves done reading cur
        if (t + 2 < NT) stage(cur, (t + 2) << 6);    // overwrite cur for tile t+2
        __builtin_amdgcn_s_setprio(1);
#pragma unroll
        for (int kk = 0; kk < 2; kk++)
#pragma unroll
            for (int mf = 0; mf < 4; mf++)
#pragma unroll
                for (int nf = 0; nf < 4; nf++)
                    acc[mf][nf] = __builtin_amdgcn_mfma_f32_16x16x32_bf16(ah[mf][kk], bh[nf][kk], acc[mf][nf], 0, 0, 0);
        __builtin_amdgcn_s_setprio(0);
        __builtin_amdgcn_sched_barrier(0);
        if (t + 2 < NT) { WAITVM(8); }               // my slice of tile t+1 landed
        else           { WAITVM(0); }
        SBAR();                                      // tile t+1 certified for all waves
    }

    // epilogue
#pragma unroll
    for (int mf = 0; mf < 4; mf++)
#pragma unroll
        for (int j = 0; j < 4; j++) {
            int row = bm * 128 + wm * 64 + mf * 16 + fh * 4 + j;
            if (EPI == 0) {
                u16* dst = (bn < 16) ? Cxi : Cz;
                const int cbase = (bn < 16) ? bn * 128 : (bn - 16) * 128;
#pragma unroll
                for (int n = 0; n < 4; n++) {
                    int col = cbase + wn * 64 + n * 16 + fl;
                    dst[(size_t)row * DI + col] = f2bf(acc[mf][n][j]);
                }
            } else {
                float t = th[row];
#pragma unroll
                for (int n = 0; n < 4; n++) {
                    int col = bn * 128 + wn * 64 + n * 16 + fl;
                    size_t idx = (size_t)row * DM + col;
                    Cf[idx] = xres[idx] + acc[mf][n][j] * __expf(-sd[col] * t);
                }
            }
        }
}

// ---------------- small GEMM (dt_proj): C[M,N] = A[M,K] * W[N,K]^T ----------------
__global__ __launch_bounds__(256) void gemm_bt(
    const u16* __restrict__ A, int lda,
    const u16* __restrict__ W,
    u16* __restrict__ Cb, int ldc,
    int M, int N, int K,
    const float* __restrict__ bias) {
    __shared__ u16 As[128 * 32];
    __shared__ u16 Bs[128 * 32];
    const int tid = threadIdx.x;
    const int wave = tid >> 6, lane = tid & 63;
    const int bm = blockIdx.x, bn = blockIdx.y;
    const int srow = lane >> 2, scol = (lane & 3) * 8;
    const int wr = wave >> 1, wc = wave & 1;
    const int fl = lane & 15, fh = lane >> 4;

    f32x4 acc[4][4];
#pragma unroll
    for (int m = 0; m < 4; m++)
#pragma unroll
        for (int n = 0; n < 4; n++) acc[m][n] = f32x4{0.f, 0.f, 0.f, 0.f};

    int ra[2], rb[2];
    u16* ldsA[2]; u16* ldsB[2];
#pragma unroll
    for (int i = 0; i < 2; i++) {
        int r = (wave * 2 + i) * 16 + srow;
        ra[i] = min(bm * 128 + r, M - 1);
        rb[i] = min(bn * 128 + r, N - 1);
        ldsA[i] = As + (wave * 2 + i) * 512 + lane * 8;
        ldsB[i] = Bs + (wave * 2 + i) * 512 + lane * 8;
    }

    for (int k0 = 0; k0 < K; k0 += 32) {
        __syncthreads();
#pragma unroll
        for (int i = 0; i < 2; i++) {
            async16(ldsA[i], A + (size_t)ra[i] * lda + k0 + scol);
            async16(ldsB[i], W + (size_t)rb[i] * K + k0 + scol);
        }
        __syncthreads();
        s16x8 av[4], bv[4];
#pragma unroll
        for (int m = 0; m < 4; m++)
            av[m] = *(const s16x8*)(As + (wr * 64 + m * 16 + fl) * 32 + fh * 8);
#pragma unroll
        for (int n = 0; n < 4; n++)
            bv[n] = *(const s16x8*)(Bs + (wc * 64 + n * 16 + fl) * 32 + fh * 8);
#pragma unroll
        for (int m = 0; m < 4; m++)
#pragma unroll
            for (int n = 0; n < 4; n++)
                acc[m][n] = __builtin_amdgcn_mfma_f32_16x16x32_bf16(av[m], bv[n], acc[m][n], 0, 0, 0);
    }

#pragma unroll
    for (int m = 0; m < 4; m++) {
#pragma unroll
        for (int j = 0; j < 4; j++) {
            int row = bm * 128 + wr * 64 + m * 16 + fh * 4 + j;
            if (row >= M) continue;
#pragma unroll
            for (int n = 0; n < 4; n++) {
                int col = bn * 128 + wc * 64 + n * 16 + fl;
                if (col >= N) continue;
                Cb[(size_t)row * ldc + col] = f2bf(softplus_f(acc[m][n][j] + bias[col]));
            }
        }
    }
}

// ---------------- x_proj split-K GEMM ----------------
__global__ __launch_bounds__(256) void xp_gemm(const u16* __restrict__ A,
                                               const u16* __restrict__ W,
                                               float* __restrict__ part) {
    __shared__ u16 As[128 * 64];
    __shared__ u16 Bs[XPN * 64];
    const int tid = threadIdx.x;
    const int wave = tid >> 6, lane = tid & 63;
    const int bm = blockIdx.x, sp = blockIdx.y;
    const int fl = lane & 15, fh = lane >> 4;
    const int trow = tid >> 3, tcol = (tid & 7) * 8;

    f32x4 acc[2][6];
#pragma unroll
    for (int m = 0; m < 2; m++)
#pragma unroll
        for (int n = 0; n < 6; n++) acc[m][n] = f32x4{0.f, 0.f, 0.f, 0.f};

    const int kbeg = sp * (DI / XP_SPLIT);
    for (int k0 = kbeg; k0 < kbeg + DI / XP_SPLIT; k0 += 64) {
        __syncthreads();
#pragma unroll
        for (int i = 0; i < 4; i++)
            async16(As + i * 2048 + tid * 8,
                    A + (size_t)(bm * 128 + i * 32 + trow) * DI + k0 + tcol);
#pragma unroll
        for (int i = 0; i < 3; i++)
            async16(Bs + i * 2048 + tid * 8,
                    W + (size_t)(i * 32 + trow) * DI + k0 + tcol);
        __syncthreads();
#pragma unroll
        for (int kk = 0; kk < 2; kk++) {
            s16x8 av[2], bv[6];
#pragma unroll
            for (int m = 0; m < 2; m++)
                av[m] = *(const s16x8*)(As + (wave * 32 + m * 16 + fl) * 64 + kk * 32 + fh * 8);
#pragma unroll
            for (int n = 0; n < 6; n++)
                bv[n] = *(const s16x8*)(Bs + (n * 16 + fl) * 64 + kk * 32 + fh * 8);
#pragma unroll
            for (int m = 0; m < 2; m++)
#pragma unroll
                for (int n = 0; n < 6; n++)
                    acc[m][n] = __builtin_amdgcn_mfma_f32_16x16x32_bf16(av[m], bv[n], acc[m][n], 0, 0, 0);
        }
    }
    float* dst = part + (size_t)sp * TOK * XPN;
#pragma unroll
    for (int m = 0; m < 2; m++)
#pragma unroll
        for (int j = 0; j < 4; j++) {
            int row = bm * 128 + wave * 32 + m * 16 + fh * 4 + j;
#pragma unroll
            for (int n = 0; n < 6; n++) {
                int col = n * 16 + fl;
                dst[(size_t)row * XPN + col] = acc[m][n][j];
            }
        }
}

__global__ __launch_bounds__(256) void xp_reduce(const float* __restrict__ part,
                                                 u16* __restrict__ out) {
    int i = blockIdx.x * 256 + threadIdx.x;
    if (i >= TOK * XPN) return;
    float s = 0.f;
#pragma unroll
    for (int sp = 0; sp < XP_SPLIT; sp++) s += part[(size_t)sp * TOK * XPN + i];
    out[i] = f2bf(s);
}

// ---------------- causal depthwise conv + silu (rolling window, packed xi) ----------------
__global__ __launch_bounds__(256) void conv_silu_kernel(const u16* __restrict__ xi,
                                                        const float* __restrict__ cw,
                                                        const float* __restrict__ cb,
                                                        u16* __restrict__ u) {
    const int b = blockIdx.y;
    const int l0 = blockIdx.x * CONV_T;
    const int d0 = threadIdx.x * 8;
    float w0[8], w1[8], w2[8], w3[8], bias[8];
#pragma unroll
    for (int e = 0; e < 8; e++) {
        float4 wv = ((const float4*)cw)[d0 + e];
        w0[e] = wv.x; w1[e] = wv.y; w2[e] = wv.z; w3[e] = wv.w;
        bias[e] = cb[d0 + e];
    }
    float win[4][8];
#pragma unroll
    for (int i = 0; i < 3; i++) {
        int l = l0 - 3 + i;
        int slot = (l0 + 1 + i) & 3;
        if (l < 0) {
#pragma unroll
            for (int e = 0; e < 8; e++) win[slot][e] = 0.f;
        } else {
            u16x8 v = *(const u16x8*)(xi + ((size_t)(b * 2048 + l)) * DI + d0);
#pragma unroll
            for (int e = 0; e < 8; e++) win[slot][e] = bf2f(v[e]);
        }
    }
#pragma unroll
    for (int t = 0; t < CONV_T; t++) {
        const int l = l0 + t;
        const size_t tok = (size_t)b * 2048 + l;
        u16x8 v = *(const u16x8*)(xi + tok * DI + d0);
        const int s3 = t & 3;
#pragma unroll
        for (int e = 0; e < 8; e++) win[s3][e] = bf2f(v[e]);
        const int s0 = (t + 1) & 3, s1 = (t + 2) & 3, s2 = (t + 3) & 3;
        u16x8 o;
#pragma unroll
        for (int e = 0; e < 8; e++) {
            float a = bias[e];
            a = fmaf(w0[e], win[s0][e], a);
            a = fmaf(w1[e], win[s1][e], a);
            a = fmaf(w2[e], win[s2][e], a);
            a = fmaf(w3[e], win[s3][e], a);
            o[e] = f2bf(a / (1.f + __expf(-a)));
        }
        *(u16x8*)(u + tok * DI + d0) = o;
    }
}

// ---------------- selective scan, chunked (NCHUNK=64, CH=32) ----------------
__global__ __launch_bounds__(256) void scan_passA(const u16* __restrict__ delta,
                                                  const u16* __restrict__ u,
                                                  const u16* __restrict__ xdbl,
                                                  const float* __restrict__ A_log,
                                                  float* __restrict__ qh,
                                                  float* __restrict__ Sarr) {
    const int d = blockIdx.x * 256 + threadIdx.x;
    const int b = blockIdx.y, c = blockIdx.z;
    float Av[16];
#pragma unroll
    for (int n = 0; n < 16; n++) Av[n] = -__expf(A_log[d * 16 + n]);
    bool fast = true;
#pragma unroll
    for (int n = 0; n < 16; n++) fast = fast && (fabsf(Av[n] + (float)(n + 1)) < 1e-4f * (n + 1));
    const bool allfast = __all(fast);

    float h[16];
#pragma unroll
    for (int n = 0; n < 16; n++) h[n] = 0.f;
    float S = 0.f;
    const int l0 = c * CH;
    size_t tok = (size_t)b * 2048 + l0;
    float dt = bf2f(delta[tok * DI + d]);
    float uu = bf2f(u[tok * DI + d]);
    const uint4* bp0 = (const uint4*)(xdbl + tok * 96 + 64);
    uint4 b0 = bp0[0], b1 = bp0[1];
    for (int t = 0; t < CH; ++t) {
        const int tn = (t + 1 < CH) ? t + 1 : t;
        const size_t tokn = (size_t)b * 2048 + l0 + tn;
        float dt_n = bf2f(delta[tokn * DI + d]);
        float uu_n = bf2f(u[tokn * DI + d]);
        const uint4* bpn = (const uint4*)(xdbl + tokn * 96 + 64);
        uint4 b0n = bpn[0], b1n = bpn[1];
        float du = dt * uu;
        float Bv[16];
        unpack8(b0, Bv); unpack8(b1, Bv + 8);
        float e[16];
        if (allfast) {
            float r = __expf(-dt);
            e[0] = r;
#pragma unroll
            for (int n = 1; n < 16; n++) e[n] = e[n - 1] * r;
        } else {
#pragma unroll
            for (int n = 0; n < 16; n++) e[n] = __expf(dt * Av[n]);
        }
#pragma unroll
        for (int n = 0; n < 16; n++) h[n] = fmaf(e[n], h[n], du * Bv[n]);
        S += dt;
        dt = dt_n; uu = uu_n; b0 = b0n; b1 = b1n;
    }
    const size_t base = ((size_t)(c * 4 + b) * 16) * DI + d;
#pragma unroll
    for (int n = 0; n < 16; n++) qh[base + (size_t)n * DI] = h[n];
    Sarr[(size_t)(c * 4 + b) * DI + d] = S;
}

__global__ __launch_bounds__(256) void scan_passB(float* __restrict__ qh,
                                                  const float* __restrict__ Sarr,
                                                  const float* __restrict__ A_log) {
    const int idx = blockIdx.x * 256 + threadIdx.x;
    const int d = idx & (DI - 1);
    const int n = (idx >> 11) & 15;
    const int b = idx >> 15;
    const float Avn = -__expf(A_log[d * 16 + n]);
    float h = 0.f;
    for (int c = 0; c < NCHUNK; c++) {
        const size_t base = ((size_t)(c * 4 + b) * 16 + n) * DI + d;
        const float qv = qh[base];
        const float S = Sarr[(size_t)(c * 4 + b) * DI + d];
        qh[base] = h;
        h = fmaf(__expf(Avn * S), h, qv);
    }
}

__global__ __launch_bounds__(256) void scan_passC(const u16* __restrict__ delta,
                                                  const u16* __restrict__ u,
                                                  const u16* __restrict__ xdbl,
                                                  const u16* __restrict__ z,
                                                  const float* __restrict__ A_log,
                                                  const float* __restrict__ Dvec,
                                                  const float* __restrict__ qh,
                                                  u16* __restrict__ yg) {
    const int d = blockIdx.x * 256 + threadIdx.x;
    const int b = blockIdx.y, c = blockIdx.z;
    float Av[16];
#pragma unroll
    for (int n = 0; n < 16; n++) Av[n] = -__expf(A_log[d * 16 + n]);
    bool fast = true;
#pragma unroll
    for (int n = 0; n < 16; n++) fast = fast && (fabsf(Av[n] + (float)(n + 1)) < 1e-4f * (n + 1));
    const bool allfast = __all(fast);
    const float Dd = Dvec[d];

    float h[16];
    const size_t hbase = ((size_t)(c * 4 + b) * 16) * DI + d;
#pragma unroll
    for (int n = 0; n < 16; n++) h[n] = qh[hbase + (size_t)n * DI];

    const int l0 = c * CH;
    size_t tok = (size_t)b * 2048 + l0;
    float dt = bf2f(delta[tok * DI + d]);
    float uu = bf2f(u[tok * DI + d]);
    float zz = bf2f(z[tok * DI + d]);
    const uint4* bp0 = (const uint4*)(xdbl + tok * 96 + 64);
    uint4 b0 = bp0[0], b1 = bp0[1], c0 = bp0[2], c1 = bp0[3];
    for (int t = 0; t < CH; ++t) {
        const int tn = (t + 1 < CH) ? t + 1 : t;
        const size_t tokn = (size_t)b * 2048 + l0 + tn;
        float dt_n = bf2f(delta[tokn * DI + d]);
        float uu_n = bf2f(u[tokn * DI + d]);
        float zz_n = bf2f(z[tokn * DI + d]);
        const uint4* bpn = (const uint4*)(xdbl + tokn * 96 + 64);
        uint4 b0n = bpn[0], b1n = bpn[1], c0n = bpn[2], c1n = bpn[3];

        float du = dt * uu;
        float Bv[16], Cv[16];
        unpack8(b0, Bv); unpack8(b1, Bv + 8);
        unpack8(c0, Cv); unpack8(c1, Cv + 8);
        float e[16];
        if (allfast) {
            float r = __expf(-dt);
            e[0] = r;
#pragma unroll
            for (int n = 1; n < 16; n++) e[n] = e[n - 1] * r;
        } else {
#pragma unroll
            for (int n = 0; n < 16; n++) e[n] = __expf(dt * Av[n]);
        }
        float y = 0.f;
#pragma unroll
        for (int n = 0; n < 16; n++) {
            h[n] = fmaf(e[n], h[n], du * Bv[n]);
            y = fmaf(h[n], Cv[n], y);
        }
        float sz = zz / (1.f + __expf(-zz));
        const size_t tokc = (size_t)b * 2048 + l0 + t;
        yg[tokc * DI + d] = f2bf((y + uu * Dd) * sz);

        dt = dt_n; uu = uu_n; zz = zz_n;
        b0 = b0n; b1 = b1n; c0 = c0n; c1 = c1n;
    }
}

// ---------------- host ----------------
extern "C" void kernel_launch(void* const* d_in, const int* in_sizes, int n_in,
                              void* d_out, int out_size, void* d_ws, size_t ws_size,
                              hipStream_t stream) {
    const float* x = (const float*)d_in[0];
    const float* tau = (const float*)d_in[1];
    const float* ln_g = (const float*)d_in[2];
    const float* ln_b = (const float*)d_in[3];
    const float* in_proj_w = (const float*)d_in[4];
    const float* conv_w = (const float*)d_in[5];
    const float* conv_b = (const float*)d_in[6];
    const float* x_proj_w = (const float*)d_in[7];
    const float* dt_proj_w = (const float*)d_in[8];
    const float* dt_proj_b = (const float*)d_in[9];
    const float* A_log = (const float*)d_in[10];
    const float* Dvec = (const float*)d_in[11];
    const float* out_proj_w = (const float*)d_in[12];
    const float* log_decay = (const float*)d_in[13];
    float* out = (float*)d_out;

    char* ws = (char*)d_ws;
    size_t off = 0;
    auto alloc = [&](size_t bytes) -> void* {
        void* p = ws + off;
        off += (bytes + 255) & ~(size_t)255;
        return p;
    };
    u16* xn    = (u16*)alloc((size_t)TOK * DM * 2);        // 16 MB (reused as xp_part)
    u16* w_in  = (u16*)alloc((size_t)2 * DI * DM * 2);     // 8 MB
    u16* w_xp  = (u16*)alloc((size_t)XPN * DI * 2);
    u16* w_dt  = (u16*)alloc((size_t)DI * DR * 2);
    u16* w_out = (u16*)alloc((size_t)DM * DI * 2);         // 4 MB
    u16* xi    = (u16*)alloc((size_t)TOK * DI * 2);        // 32 MB (conv branch, packed)
    u16* z     = (u16*)alloc((size_t)TOK * DI * 2);        // 32 MB (gate branch, packed)
    u16* u     = (u16*)alloc((size_t)TOK * DI * 2);        // 32 MB
    u16* xdbl  = (u16*)alloc((size_t)TOK * XPN * 2);       // 1.5 MB
    u16* delta = (u16*)alloc((size_t)TOK * DI * 2);        // 32 MB
    float* qh   = (float*)alloc((size_t)NCHUNK * 4 * 16 * DI * 4);  // 32 MB
    float* Sarr = (float*)alloc((size_t)NCHUNK * 4 * DI * 4);       // 2 MB
    u16* yg    = (u16*)alloc((size_t)TOK * DI * 2);        // 32 MB
    float* th = (float*)alloc((size_t)TOK * 4);
    float* sd = (float*)alloc((size_t)DM * 4);
    float* xp_part = (float*)xn;   // overlay: xn dead after in_proj

    // fused weight cvt + prep (4096 + 192 + 128 + 2048 + 32 blocks)
    cvt_all<<<6496, 256, 0, stream>>>(in_proj_w, x_proj_w, dt_proj_w, out_proj_w,
                                      tau, log_decay, w_in, w_xp, w_dt, w_out, th, sd);

    // LN
    ln_kernel<<<TOK, 256, 0, stream>>>(x, ln_g, ln_b, xn);

    // in_proj: [8192,1024] x [4096,1024]^T -> xi, z bf16 [8192,2048] each
    gemm128<0><<<2048, 256, 0, stream>>>(xn, DM, w_in, DM, DM, xi, z,
                                         nullptr, nullptr, nullptr, nullptr);
    // conv + silu -> u bf16 [8192,2048]
    conv_silu_kernel<<<dim3(2048 / CONV_T, 4), 256, 0, stream>>>(xi, conv_w, conv_b, u);

    // x_proj split-K: [8192,2048] x [96,2048]^T
    xp_gemm<<<dim3(64, XP_SPLIT), 256, 0, stream>>>(u, w_xp, xp_part);
    xp_reduce<<<(TOK * XPN + 255) / 256, 256, 0, stream>>>(xp_part, xdbl);

    // dt_proj + softplus: [8192,64] x [2048,64]^T -> delta bf16 [8192,2048]
    gemm_bt<<<dim3(64, 16), 256, 0, stream>>>(xdbl, XPN, w_dt, delta, DI,
                                              TOK, DI, DR, dt_proj_b);

    // chunked selective scan
    scan_passA<<<dim3(8, 4, NCHUNK), 256, 0, stream>>>(delta, u, xdbl, A_log, qh, Sarr);
    scan_passB<<<512, 256, 0, stream>>>(qh, Sarr, A_log);
    scan_passC<<<dim3(8, 4, NCHUNK), 256, 0, stream>>>(delta, u, xdbl, z, A_log, Dvec, qh, yg);

    // out_proj + gate + residual: [8192,2048] x [1024,2048]^T -> out f32 (fused epilogue)
    gemm128<2><<<512, 256, 0, stream>>>(yg, DI, w_out, DI, DI, nullptr, nullptr,
                                        out, x, th, sd);
}

// Round 11
// 280.125 us; speedup vs baseline: 1.0976x; 1.0976x over previous
//
#include <hip/hip_runtime.h>

typedef unsigned short u16;
typedef unsigned int u32;
typedef short s16x8 __attribute__((ext_vector_type(8)));
typedef u16 u16x8 __attribute__((ext_vector_type(8)));
typedef float f32x4 __attribute__((ext_vector_type(4)));

#define TOK 8192
#define DM 1024
#define DI 2048
#define DS 16
#define DR 64
#define NCHUNK 64
#define CH 32
#define XPN 96
#define XP_SPLIT 4
#define CONV_T 16

#define SBAR() do { asm volatile("" ::: "memory"); __builtin_amdgcn_s_barrier(); asm volatile("" ::: "memory"); } while (0)
#define WAITVM(N) do { asm volatile("s_waitcnt vmcnt(" #N ")" ::: "memory"); __builtin_amdgcn_sched_barrier(0); } while (0)
#define WAITLGKM0() do { asm volatile("s_waitcnt lgkmcnt(0)" ::: "memory"); __builtin_amdgcn_sched_barrier(0); } while (0)

__device__ __forceinline__ u16 f2bf(float f) {
    u32 u = __float_as_uint(f);
    u32 r = (u + 0x7fffu + ((u >> 16) & 1u)) >> 16;
    return (u16)r;
}
__device__ __forceinline__ float bf2f(u16 h) {
    return __uint_as_float(((u32)h) << 16);
}
// fast softplus: v_exp_f32 + v_log_f32 (~4 VALU) instead of OCML log1pf (r5: 80us VALU-bound epilogue)
__device__ __forceinline__ float softplus_f(float x) {
    return (x > 15.f) ? x : __logf(1.f + __expf(x));
}
__device__ __forceinline__ void unpack8(const uint4 v, float* o) {
    o[0] = __uint_as_float(v.x << 16); o[1] = __uint_as_float(v.x & 0xffff0000u);
    o[2] = __uint_as_float(v.y << 16); o[3] = __uint_as_float(v.y & 0xffff0000u);
    o[4] = __uint_as_float(v.z << 16); o[5] = __uint_as_float(v.z & 0xffff0000u);
    o[6] = __uint_as_float(v.w << 16); o[7] = __uint_as_float(v.w & 0xffff0000u);
}
__device__ __forceinline__ void async16(u16* lds, const u16* g) {
    __builtin_amdgcn_global_load_lds(
        (const __attribute__((address_space(1))) void*)g,
        (__attribute__((address_space(3))) void*)lds, 16, 0, 0);
}

// ---- fused: weight cvt (f32->bf16) + th/sd prep + LayerNorm (all independent) ----
__global__ __launch_bounds__(256) void prep_all(
    const float* __restrict__ in_w, const float* __restrict__ xp_w,
    const float* __restrict__ dt_w, const float* __restrict__ out_w,
    const float* __restrict__ tau, const float* __restrict__ log_decay,
    const float* __restrict__ x, const float* __restrict__ ln_g,
    const float* __restrict__ ln_b,
    u16* __restrict__ wi, u16* __restrict__ wxp, u16* __restrict__ wdt,
    u16* __restrict__ wout, float* __restrict__ th, float* __restrict__ sd,
    u16* __restrict__ xn) {
    const int b = blockIdx.x;
    if (b >= 6496) {
        // -------- LayerNorm part: one block per token --------
        const int tok = b - 6496;
        const float4 v = ((const float4*)(x + (size_t)tok * DM))[threadIdx.x];
        float s = v.x + v.y + v.z + v.w;
        float sq = v.x * v.x + v.y * v.y + v.z * v.z + v.w * v.w;
#pragma unroll
        for (int off = 32; off; off >>= 1) {
            s += __shfl_xor(s, off);
            sq += __shfl_xor(sq, off);
        }
        __shared__ float red[8];
        const int wv = threadIdx.x >> 6;
        if ((threadIdx.x & 63) == 0) { red[wv] = s; red[4 + wv] = sq; }
        __syncthreads();
        s = red[0] + red[1] + red[2] + red[3];
        sq = red[4] + red[5] + red[6] + red[7];
        const float mean = s * (1.f / DM);
        const float var = sq * (1.f / DM) - mean * mean;
        const float rstd = rsqrtf(var + 1e-5f);
        const float4 gv = ((const float4*)ln_g)[threadIdx.x];
        const float4 bv = ((const float4*)ln_b)[threadIdx.x];
        ushort4 o;
        o.x = f2bf((v.x - mean) * rstd * gv.x + bv.x);
        o.y = f2bf((v.y - mean) * rstd * gv.y + bv.y);
        o.z = f2bf((v.z - mean) * rstd * gv.z + bv.z);
        o.w = f2bf((v.w - mean) * rstd * gv.w + bv.w);
        ((ushort4*)(xn + (size_t)tok * DM))[threadIdx.x] = o;
        return;
    }
    const float* src; u16* dst; int i;
    if (b < 4096)      { src = in_w;  dst = wi;   i = b * 256 + threadIdx.x; }
    else if (b < 4288) { src = xp_w;  dst = wxp;  i = (b - 4096) * 256 + threadIdx.x; }
    else if (b < 4416) { src = dt_w;  dst = wdt;  i = (b - 4288) * 256 + threadIdx.x; }
    else if (b < 6464) { src = out_w; dst = wout; i = (b - 4416) * 256 + threadIdx.x; }
    else {
        int j = (b - 6464) * 256 + threadIdx.x;
        if (j < TOK) th[j] = fmaxf(tau[j] * (1.f / 3600.f), 1e-4f);
        if (j < DM)  sd[j] = softplus_f(log_decay[j]);
        return;
    }
    float4 v = ((const float4*)src)[i];
    ushort4 o;
    o.x = f2bf(v.x); o.y = f2bf(v.y); o.z = f2bf(v.z); o.w = f2bf(v.w);
    ((ushort4*)dst)[i] = o;
}

// ============ 128x128 GEMM, BK=64, 4 waves (2m x 2n), dbuf=2, 2 blocks/CU ============
// r8/r9 lesson: with ONE block/CU all waves are barrier-lockstep, so per-tile LDS reads
// serialize with MFMA. Two INDEPENDENT blocks/CU (64KB LDS, launch_bounds(256,2)) let
// block A's MFMA cluster overlap block B's ds_read/stage section.
// EPI 0 (in_proj): C -> xi (cols<2048) / z (cols>=2048), bf16.
// EPI 2 (out_proj): Cf = xres + C * exp(-sd[col]*th[row]), f32.
template <int EPI>
__global__ __launch_bounds__(256, 2) void gemm128(
    const u16* __restrict__ A, int lda,
    const u16* __restrict__ W, int ldw, int K,
    u16* __restrict__ Cxi, u16* __restrict__ Cz,
    float* __restrict__ Cf,
    const float* __restrict__ xres, const float* __restrict__ th,
    const float* __restrict__ sd) {
    __shared__ __align__(16) u16 lds[2 * 16384];  // 64 KB: per buf A 16KB + B 16KB
    const int tid = threadIdx.x;
    const int wave = tid >> 6, lane = tid & 63;
    const int wm = wave >> 1, wn = wave & 1;
    const int fl = lane & 15, fh = lane >> 4;
    // XCD swizzle + 2-D L2 region blocking
    int bm, bn;
    if (EPI == 0) {
        // in_proj: 2048 blocks, 256/XCD; region 4bm x 8bn (A 1MB + W 2MB = 3MB <= L2)
        const int swz = ((int)blockIdx.x & 7) * 256 + ((int)blockIdx.x >> 3);
        const int rg = swz >> 5, wi_ = swz & 31;
        bm = (rg >> 2) * 4 + (wi_ >> 3);   // 0..63
        bn = (rg & 3) * 8 + (wi_ & 7);     // 0..31
    } else {
        // out_proj: 512 blocks, 64/XCD; region 4bm x 4bn (A 2MB + W 2MB = 4MB = L2)
        const int swz = ((int)blockIdx.x & 7) * 64 + ((int)blockIdx.x >> 3);
        const int rg = swz >> 4, wi_ = swz & 15;
        bm = (rg >> 1) * 4 + (wi_ >> 2);   // 0..63
        bn = (rg & 1) * 4 + (wi_ & 3);     // 0..7
    }
    const int NT = K >> 6;

    const int r0 = tid >> 3;                         // 0..31
    const int cb = ((tid & 7) ^ (r0 & 7)) << 3;      // pre-swizzled col (elems)
    const int rA = bm * 128 + r0;
    const int rB = bn * 128 + r0;

    f32x4 acc[4][4];
#pragma unroll
    for (int m = 0; m < 4; m++)
#pragma unroll
        for (int n = 0; n < 4; n++) acc[m][n] = f32x4{0.f, 0.f, 0.f, 0.f};

    auto stage = [&](int buf, int k0) {
#pragma unroll
        for (int j = 0; j < 4; j++)
            async16(lds + buf * 16384 + j * 2048 + tid * 8,
                    A + (size_t)(rA + j * 32) * lda + k0 + cb);
#pragma unroll
        for (int j = 0; j < 4; j++)
            async16(lds + buf * 16384 + 8192 + j * 2048 + tid * 8,
                    W + (size_t)(rB + j * 32) * ldw + k0 + cb);
    };
    auto rdA = [&](int buf, int mf, int kk) -> s16x8 {
        int r = wm * 64 + mf * 16 + fl;
        int slot = ((kk << 2) | fh) ^ (fl & 7);
        return *(const s16x8*)(lds + buf * 16384 + r * 64 + slot * 8);
    };
    auto rdB = [&](int buf, int nf, int kk) -> s16x8 {
        int r = wn * 64 + nf * 16 + fl;
        int slot = ((kk << 2) | fh) ^ (fl & 7);
        return *(const s16x8*)(lds + buf * 16384 + 8192 + r * 64 + slot * 8);
    };

    // prologue: stage tile0 -> buf0, tile1 -> buf1; certify tile0 for all waves
    stage(0, 0);
    stage(1, 64);
    WAITVM(8);
    SBAR();

    for (int t = 0; t < NT; ++t) {
        const int cur = t & 1;
        s16x8 ah[4][2], bh[4][2];
#pragma unroll
        for (int mf = 0; mf < 4; mf++) { ah[mf][0] = rdA(cur, mf, 0); ah[mf][1] = rdA(cur, mf, 1); }
#pragma unroll
        for (int nf = 0; nf < 4; nf++) { bh[nf][0] = rdB(cur, nf, 0); bh[nf][1] = rdB(cur, nf, 1); }
        WAITLGKM0();
        SBAR();                                      // all waves done reading cur
        if (t + 2 < NT) stage(cur, (t + 2) << 6);    // overwrite cur for tile t+2
        __builtin_amdgcn_s_setprio(1);
#pragma unroll
        for (int kk = 0; kk < 2; kk++)
#pragma unroll
            for (int mf = 0; mf < 4; mf++)
#pragma unroll
                for (int nf = 0; nf < 4; nf++)
                    acc[mf][nf] = __builtin_amdgcn_mfma_f32_16x16x32_bf16(ah[mf][kk], bh[nf][kk], acc[mf][nf], 0, 0, 0);
        __builtin_amdgcn_s_setprio(0);
        __builtin_amdgcn_sched_barrier(0);
        if (t + 2 < NT) { WAITVM(8); }               // my slice of tile t+1 landed
        else           { WAITVM(0); }
        SBAR();                                      // tile t+1 certified for all waves
    }

    // epilogue
#pragma unroll
    for (int mf = 0; mf < 4; mf++)
#pragma unroll
        for (int j = 0; j < 4; j++) {
            int row = bm * 128 + wm * 64 + mf * 16 + fh * 4 + j;
            if (EPI == 0) {
                u16* dst = (bn < 16) ? Cxi : Cz;
                const int cbase = (bn < 16) ? bn * 128 : (bn - 16) * 128;
#pragma unroll
                for (int n = 0; n < 4; n++) {
                    int col = cbase + wn * 64 + n * 16 + fl;
                    dst[(size_t)row * DI + col] = f2bf(acc[mf][n][j]);
                }
            } else {
                float t = th[row];
#pragma unroll
                for (int n = 0; n < 4; n++) {
                    int col = bn * 128 + wn * 64 + n * 16 + fl;
                    size_t idx = (size_t)row * DM + col;
                    Cf[idx] = xres[idx] + acc[mf][n][j] * __expf(-sd[col] * t);
                }
            }
        }
}

// -------- dt_proj GEMM, single K-tile (K=64): delta = softplus(xdbl[:, :64] W^T + b) --------
// 128x128 tile, 4 waves (2m x 2n), one 32KB stage, 2 barriers total, 32 MFMA.
__global__ __launch_bounds__(256) void dt_gemm(
    const u16* __restrict__ A,      // xdbl [8192, 96], cols 0..63 used
    const u16* __restrict__ W,      // w_dt [2048, 64]
    u16* __restrict__ Cb,           // delta [8192, 2048]
    const float* __restrict__ bias) {
    __shared__ __align__(16) u16 lds[2 * 8192];  // A 16KB + B 16KB
    const int tid = threadIdx.x;
    const int wave = tid >> 6, lane = tid & 63;
    const int wm = wave >> 1, wn = wave & 1;
    const int fl = lane & 15, fh = lane >> 4;
    const int bm = blockIdx.x, bn = blockIdx.y;

    const int r0 = tid >> 3;
    const int cb = ((tid & 7) ^ (r0 & 7)) << 3;      // pre-swizzled col within 64

#pragma unroll
    for (int j = 0; j < 4; j++)
        async16(lds + j * 2048 + tid * 8,
                A + (size_t)(bm * 128 + j * 32 + r0) * XPN + cb);
#pragma unroll
    for (int j = 0; j < 4; j++)
        async16(lds + 8192 + j * 2048 + tid * 8,
                W + (size_t)(bn * 128 + j * 32 + r0) * DR + cb);
    WAITVM(0);
    SBAR();

    auto rdA = [&](int mf, int kk) -> s16x8 {
        int r = wm * 64 + mf * 16 + fl;
        int slot = ((kk << 2) | fh) ^ (fl & 7);
        return *(const s16x8*)(lds + r * 64 + slot * 8);
    };
    auto rdB = [&](int nf, int kk) -> s16x8 {
        int r = wn * 64 + nf * 16 + fl;
        int slot = ((kk << 2) | fh) ^ (fl & 7);
        return *(const s16x8*)(lds + 8192 + r * 64 + slot * 8);
    };

    f32x4 acc[4][4];
#pragma unroll
    for (int m = 0; m < 4; m++)
#pragma unroll
        for (int n = 0; n < 4; n++) acc[m][n] = f32x4{0.f, 0.f, 0.f, 0.f};

    s16x8 ah[4][2], bh[4][2];
#pragma unroll
    for (int mf = 0; mf < 4; mf++) { ah[mf][0] = rdA(mf, 0); ah[mf][1] = rdA(mf, 1); }
#pragma unroll
    for (int nf = 0; nf < 4; nf++) { bh[nf][0] = rdB(nf, 0); bh[nf][1] = rdB(nf, 1); }
    WAITLGKM0();
#pragma unroll
    for (int kk = 0; kk < 2; kk++)
#pragma unroll
        for (int mf = 0; mf < 4; mf++)
#pragma unroll
            for (int nf = 0; nf < 4; nf++)
                acc[mf][nf] = __builtin_amdgcn_mfma_f32_16x16x32_bf16(ah[mf][kk], bh[nf][kk], acc[mf][nf], 0, 0, 0);

#pragma unroll
    for (int mf = 0; mf < 4; mf++)
#pragma unroll
        for (int j = 0; j < 4; j++) {
            int row = bm * 128 + wm * 64 + mf * 16 + fh * 4 + j;
#pragma unroll
            for (int n = 0; n < 4; n++) {
                int col = bn * 128 + wn * 64 + n * 16 + fl;
                Cb[(size_t)row * DI + col] = f2bf(softplus_f(acc[mf][n][j] + bias[col]));
            }
        }
}

// ---------------- x_proj split-K GEMM ----------------
__global__ __launch_bounds__(256) void xp_gemm(const u16* __restrict__ A,
                                               const u16* __restrict__ W,
                                               float* __restrict__ part) {
    __shared__ u16 As[128 * 64];
    __shared__ u16 Bs[XPN * 64];
    const int tid = threadIdx.x;
    const int wave = tid >> 6, lane = tid & 63;
    const int bm = blockIdx.x, sp = blockIdx.y;
    const int fl = lane & 15, fh = lane >> 4;
    const int trow = tid >> 3, tcol = (tid & 7) * 8;

    f32x4 acc[2][6];
#pragma unroll
    for (int m = 0; m < 2; m++)
#pragma unroll
        for (int n = 0; n < 6; n++) acc[m][n] = f32x4{0.f, 0.f, 0.f, 0.f};

    const int kbeg = sp * (DI / XP_SPLIT);
    for (int k0 = kbeg; k0 < kbeg + DI / XP_SPLIT; k0 += 64) {
        __syncthreads();
#pragma unroll
        for (int i = 0; i < 4; i++)
            async16(As + i * 2048 + tid * 8,
                    A + (size_t)(bm * 128 + i * 32 + trow) * DI + k0 + tcol);
#pragma unroll
        for (int i = 0; i < 3; i++)
            async16(Bs + i * 2048 + tid * 8,
                    W + (size_t)(i * 32 + trow) * DI + k0 + tcol);
        __syncthreads();
#pragma unroll
        for (int kk = 0; kk < 2; kk++) {
            s16x8 av[2], bv[6];
#pragma unroll
            for (int m = 0; m < 2; m++)
                av[m] = *(const s16x8*)(As + (wave * 32 + m * 16 + fl) * 64 + kk * 32 + fh * 8);
#pragma unroll
            for (int n = 0; n < 6; n++)
                bv[n] = *(const s16x8*)(Bs + (n * 16 + fl) * 64 + kk * 32 + fh * 8);
#pragma unroll
            for (int m = 0; m < 2; m++)
#pragma unroll
                for (int n = 0; n < 6; n++)
                    acc[m][n] = __builtin_amdgcn_mfma_f32_16x16x32_bf16(av[m], bv[n], acc[m][n], 0, 0, 0);
        }
    }
    float* dst = part + (size_t)sp * TOK * XPN;
#pragma unroll
    for (int m = 0; m < 2; m++)
#pragma unroll
        for (int j = 0; j < 4; j++) {
            int row = bm * 128 + wave * 32 + m * 16 + fh * 4 + j;
#pragma unroll
            for (int n = 0; n < 6; n++) {
                int col = n * 16 + fl;
                dst[(size_t)row * XPN + col] = acc[m][n][j];
            }
        }
}

__global__ __launch_bounds__(256) void xp_reduce(const float* __restrict__ part,
                                                 u16* __restrict__ out) {
    int i = blockIdx.x * 256 + threadIdx.x;
    if (i >= TOK * XPN) return;
    float s = 0.f;
#pragma unroll
    for (int sp = 0; sp < XP_SPLIT; sp++) s += part[(size_t)sp * TOK * XPN + i];
    out[i] = f2bf(s);
}

// ---------------- causal depthwise conv + silu (rolling window, packed xi) ----------------
__global__ __launch_bounds__(256) void conv_silu_kernel(const u16* __restrict__ xi,
                                                        const float* __restrict__ cw,
                                                        const float* __restrict__ cb,
                                                        u16* __restrict__ u) {
    const int b = blockIdx.y;
    const int l0 = blockIdx.x * CONV_T;
    const int d0 = threadIdx.x * 8;
    float w0[8], w1[8], w2[8], w3[8], bias[8];
#pragma unroll
    for (int e = 0; e < 8; e++) {
        float4 wv = ((const float4*)cw)[d0 + e];
        w0[e] = wv.x; w1[e] = wv.y; w2[e] = wv.z; w3[e] = wv.w;
        bias[e] = cb[d0 + e];
    }
    float win[4][8];
#pragma unroll
    for (int i = 0; i < 3; i++) {
        int l = l0 - 3 + i;
        int slot = (l0 + 1 + i) & 3;
        if (l < 0) {
#pragma unroll
            for (int e = 0; e < 8; e++) win[slot][e] = 0.f;
        } else {
            u16x8 v = *(const u16x8*)(xi + ((size_t)(b * 2048 + l)) * DI + d0);
#pragma unroll
            for (int e = 0; e < 8; e++) win[slot][e] = bf2f(v[e]);
        }
    }
#pragma unroll
    for (int t = 0; t < CONV_T; t++) {
        const int l = l0 + t;
        const size_t tok = (size_t)b * 2048 + l;
        u16x8 v = *(const u16x8*)(xi + tok * DI + d0);
        const int s3 = t & 3;
#pragma unroll
        for (int e = 0; e < 8; e++) win[s3][e] = bf2f(v[e]);
        const int s0 = (t + 1) & 3, s1 = (t + 2) & 3, s2 = (t + 3) & 3;
        u16x8 o;
#pragma unroll
        for (int e = 0; e < 8; e++) {
            float a = bias[e];
            a = fmaf(w0[e], win[s0][e], a);
            a = fmaf(w1[e], win[s1][e], a);
            a = fmaf(w2[e], win[s2][e], a);
            a = fmaf(w3[e], win[s3][e], a);
            o[e] = f2bf(a / (1.f + __expf(-a)));
        }
        *(u16x8*)(u + tok * DI + d0) = o;
    }
}

// ---------------- selective scan, chunked (NCHUNK=64, CH=32), qh in bf16 ----------------
__global__ __launch_bounds__(256) void scan_passA(const u16* __restrict__ delta,
                                                  const u16* __restrict__ u,
                                                  const u16* __restrict__ xdbl,
                                                  const float* __restrict__ A_log,
                                                  u16* __restrict__ qh,
                                                  float* __restrict__ Sarr) {
    const int d = blockIdx.x * 256 + threadIdx.x;
    const int b = blockIdx.y, c = blockIdx.z;
    float Av[16];
#pragma unroll
    for (int n = 0; n < 16; n++) Av[n] = -__expf(A_log[d * 16 + n]);
    bool fast = true;
#pragma unroll
    for (int n = 0; n < 16; n++) fast = fast && (fabsf(Av[n] + (float)(n + 1)) < 1e-4f * (n + 1));
    const bool allfast = __all(fast);

    float h[16];
#pragma unroll
    for (int n = 0; n < 16; n++) h[n] = 0.f;
    float S = 0.f;
    const int l0 = c * CH;
    size_t tok = (size_t)b * 2048 + l0;
    float dt = bf2f(delta[tok * DI + d]);
    float uu = bf2f(u[tok * DI + d]);
    const uint4* bp0 = (const uint4*)(xdbl + tok * 96 + 64);
    uint4 b0 = bp0[0], b1 = bp0[1];
    for (int t = 0; t < CH; ++t) {
        const int tn = (t + 1 < CH) ? t + 1 : t;
        const size_t tokn = (size_t)b * 2048 + l0 + tn;
        float dt_n = bf2f(delta[tokn * DI + d]);
        float uu_n = bf2f(u[tokn * DI + d]);
        const uint4* bpn = (const uint4*)(xdbl + tokn * 96 + 64);
        uint4 b0n = bpn[0], b1n = bpn[1];
        float du = dt * uu;
        float Bv[16];
        unpack8(b0, Bv); unpack8(b1, Bv + 8);
        float e[16];
        if (allfast) {
            float r = __expf(-dt);
            e[0] = r;
#pragma unroll
            for (int n = 1; n < 16; n++) e[n] = e[n - 1] * r;
        } else {
#pragma unroll
            for (int n = 0; n < 16; n++) e[n] = __expf(dt * Av[n]);
        }
#pragma unroll
        for (int n = 0; n < 16; n++) h[n] = fmaf(e[n], h[n], du * Bv[n]);
        S += dt;
        dt = dt_n; uu = uu_n; b0 = b0n; b1 = b1n;
    }
    const size_t base = ((size_t)(c * 4 + b) * 16) * DI + d;
#pragma unroll
    for (int n = 0; n < 16; n++) qh[base + (size_t)n * DI] = f2bf(h[n]);
    Sarr[(size_t)(c * 4 + b) * DI + d] = S;
}

__global__ __launch_bounds__(256) void scan_passB(u16* __restrict__ qh,
                                                  const float* __restrict__ Sarr,
                                                  const float* __restrict__ A_log) {
    const int idx = blockIdx.x * 256 + threadIdx.x;
    const int d = idx & (DI - 1);
    const int n = (idx >> 11) & 15;
    const int b = idx >> 15;
    const float Avn = -__expf(A_log[d * 16 + n]);
    float h = 0.f;
    for (int c = 0; c < NCHUNK; c++) {
        const size_t base = ((size_t)(c * 4 + b) * 16 + n) * DI + d;
        const float qv = bf2f(qh[base]);
        const float S = Sarr[(size_t)(c * 4 + b) * DI + d];
        qh[base] = f2bf(h);
        h = fmaf(__expf(Avn * S), h, qv);
    }
}

__global__ __launch_bounds__(256) void scan_passC(const u16* __restrict__ delta,
                                                  const u16* __restrict__ u,
                                                  const u16* __restrict__ xdbl,
                                                  const u16* __restrict__ z,
                                                  const float* __restrict__ A_log,
                                                  const float* __restrict__ Dvec,
                                                  const u16* __restrict__ qh,
                                                  u16* __restrict__ yg) {
    const int d = blockIdx.x * 256 + threadIdx.x;
    const int b = blockIdx.y, c = blockIdx.z;
    float Av[16];
#pragma unroll
    for (int n = 0; n < 16; n++) Av[n] = -__expf(A_log[d * 16 + n]);
    bool fast = true;
#pragma unroll
    for (int n = 0; n < 16; n++) fast = fast && (fabsf(Av[n] + (float)(n + 1)) < 1e-4f * (n + 1));
    const bool allfast = __all(fast);
    const float Dd = Dvec[d];

    float h[16];
    const size_t hbase = ((size_t)(c * 4 + b) * 16) * DI + d;
#pragma unroll
    for (int n = 0; n < 16; n++) h[n] = bf2f(qh[hbase + (size_t)n * DI]);

    const int l0 = c * CH;
    size_t tok = (size_t)b * 2048 + l0;
    float dt = bf2f(delta[tok * DI + d]);
    float uu = bf2f(u[tok * DI + d]);
    float zz = bf2f(z[tok * DI + d]);
    const uint4* bp0 = (const uint4*)(xdbl + tok * 96 + 64);
    uint4 b0 = bp0[0], b1 = bp0[1], c0 = bp0[2], c1 = bp0[3];
    for (int t = 0; t < CH; ++t) {
        const int tn = (t + 1 < CH) ? t + 1 : t;
        const size_t tokn = (size_t)b * 2048 + l0 + tn;
        float dt_n = bf2f(delta[tokn * DI + d]);
        float uu_n = bf2f(u[tokn * DI + d]);
        float zz_n = bf2f(z[tokn * DI + d]);
        const uint4* bpn = (const uint4*)(xdbl + tokn * 96 + 64);
        uint4 b0n = bpn[0], b1n = bpn[1], c0n = bpn[2], c1n = bpn[3];

        float du = dt * uu;
        float Bv[16], Cv[16];
        unpack8(b0, Bv); unpack8(b1, Bv + 8);
        unpack8(c0, Cv); unpack8(c1, Cv + 8);
        float e[16];
        if (allfast) {
            float r = __expf(-dt);
            e[0] = r;
#pragma unroll
            for (int n = 1; n < 16; n++) e[n] = e[n - 1] * r;
        } else {
#pragma unroll
            for (int n = 0; n < 16; n++) e[n] = __expf(dt * Av[n]);
        }
        float y = 0.f;
#pragma unroll
        for (int n = 0; n < 16; n++) {
            h[n] = fmaf(e[n], h[n], du * Bv[n]);
            y = fmaf(h[n], Cv[n], y);
        }
        float sz = zz / (1.f + __expf(-zz));
        const size_t tokc = (size_t)b * 2048 + l0 + t;
        yg[tokc * DI + d] = f2bf((y + uu * Dd) * sz);

        dt = dt_n; uu = uu_n; zz = zz_n;
        b0 = b0n; b1 = b1n; c0 = c0n; c1 = c1n;
    }
}

// ---------------- host ----------------
extern "C" void kernel_launch(void* const* d_in, const int* in_sizes, int n_in,
                              void* d_out, int out_size, void* d_ws, size_t ws_size,
                              hipStream_t stream) {
    const float* x = (const float*)d_in[0];
    const float* tau = (const float*)d_in[1];
    const float* ln_g = (const float*)d_in[2];
    const float* ln_b = (const float*)d_in[3];
    const float* in_proj_w = (const float*)d_in[4];
    const float* conv_w = (const float*)d_in[5];
    const float* conv_b = (const float*)d_in[6];
    const float* x_proj_w = (const float*)d_in[7];
    const float* dt_proj_w = (const float*)d_in[8];
    const float* dt_proj_b = (const float*)d_in[9];
    const float* A_log = (const float*)d_in[10];
    const float* Dvec = (const float*)d_in[11];
    const float* out_proj_w = (const float*)d_in[12];
    const float* log_decay = (const float*)d_in[13];
    float* out = (float*)d_out;

    char* ws = (char*)d_ws;
    size_t off = 0;
    auto alloc = [&](size_t bytes) -> void* {
        void* p = ws + off;
        off += (bytes + 255) & ~(size_t)255;
        return p;
    };
    u16* xn    = (u16*)alloc((size_t)TOK * DM * 2);        // 16 MB (reused as xp_part)
    u16* w_in  = (u16*)alloc((size_t)2 * DI * DM * 2);     // 8 MB
    u16* w_xp  = (u16*)alloc((size_t)XPN * DI * 2);
    u16* w_dt  = (u16*)alloc((size_t)DI * DR * 2);
    u16* w_out = (u16*)alloc((size_t)DM * DI * 2);         // 4 MB
    u16* xi    = (u16*)alloc((size_t)TOK * DI * 2);        // 32 MB (conv branch, packed)
    u16* z     = (u16*)alloc((size_t)TOK * DI * 2);        // 32 MB (gate branch, packed)
    u16* u     = (u16*)alloc((size_t)TOK * DI * 2);        // 32 MB
    u16* xdbl  = (u16*)alloc((size_t)TOK * XPN * 2);       // 1.5 MB
    u16* delta = (u16*)alloc((size_t)TOK * DI * 2);        // 32 MB
    u16* qh    = (u16*)alloc((size_t)NCHUNK * 4 * 16 * DI * 2);  // 16 MB (bf16)
    float* Sarr = (float*)alloc((size_t)NCHUNK * 4 * DI * 4);     // 2 MB
    u16* yg    = (u16*)alloc((size_t)TOK * DI * 2);        // 32 MB
    float* th = (float*)alloc((size_t)TOK * 4);
    float* sd = (float*)alloc((size_t)DM * 4);
    float* xp_part = (float*)xn;   // overlay: xn dead after in_proj

    // fused weight cvt + prep + LayerNorm (6496 cvt/prep blocks + 8192 ln blocks)
    prep_all<<<6496 + TOK, 256, 0, stream>>>(in_proj_w, x_proj_w, dt_proj_w, out_proj_w,
                                             tau, log_decay, x, ln_g, ln_b,
                                             w_in, w_xp, w_dt, w_out, th, sd, xn);

    // in_proj: [8192,1024] x [4096,1024]^T -> xi, z bf16 [8192,2048] each
    gemm128<0><<<2048, 256, 0, stream>>>(xn, DM, w_in, DM, DM, xi, z,
                                         nullptr, nullptr, nullptr, nullptr);
    // conv + silu -> u bf16 [8192,2048]
    conv_silu_kernel<<<dim3(2048 / CONV_T, 4), 256, 0, stream>>>(xi, conv_w, conv_b, u);

    // x_proj split-K: [8192,2048] x [96,2048]^T
    xp_gemm<<<dim3(64, XP_SPLIT), 256, 0, stream>>>(u, w_xp, xp_part);
    xp_reduce<<<(TOK * XPN + 255) / 256, 256, 0, stream>>>(xp_part, xdbl);

    // dt_proj + softplus (single K-tile): [8192,64] x [2048,64]^T -> delta bf16
    dt_gemm<<<dim3(64, 16), 256, 0, stream>>>(xdbl, w_dt, delta, dt_proj_b);

    // chunked selective scan (qh bf16)
    scan_passA<<<dim3(8, 4, NCHUNK), 256, 0, stream>>>(delta, u, xdbl, A_log, qh, Sarr);
    scan_passB<<<512, 256, 0, stream>>>(qh, Sarr, A_log);
    scan_passC<<<dim3(8, 4, NCHUNK), 256, 0, stream>>>(delta, u, xdbl, z, A_log, Dvec, qh, yg);

    // out_proj + gate + residual: [8192,2048] x [1024,2048]^T -> out f32 (fused epilogue)
    gemm128<2><<<512, 256, 0, stream>>>(yg, DI, w_out, DI, DI, nullptr, nullptr,
                                        out, x, th, sd);
}